// Round 1
// baseline (373.030 us; speedup 1.0000x reference)
//
#include <hip/hip_runtime.h>

// ForceMapping: out[b,a,x] = sum_n ( ssp(E[b,a,n,:] @ W1 + b1) @ W2 + b2 ) * u[b,a,n,x]
// B=16, At=512, Nbr=64, F=128, H=64. 8192 atoms, 64 edges each.

typedef __attribute__((ext_vector_type(8))) short short8;   // 8 bf16 = 4 VGPRs (MFMA A/B frag)
typedef __attribute__((ext_vector_type(4))) float f32x4;    // MFMA C/D frag

__device__ __forceinline__ unsigned bf16rn(float f) {
    unsigned u = __float_as_uint(f);
    unsigned r = 0x7FFFu + ((u >> 16) & 1u);   // round-to-nearest-even
    return (u + r) >> 16;
}
__device__ __forceinline__ unsigned pack2(float lo, float hi) {
    return bf16rn(lo) | (bf16rn(hi) << 16);
}

// Setup: pre-swizzle W1 (128x64 fp32, row-major [f][h]) into bf16 B-fragments in
// per-lane MFMA order. frag t = kk*4+nn; lane holds B[k=kk*32+q*8+j][n=nn*16+c], j=0..7.
// Table: 16 frags x 64 lanes x 8 bf16 = 16 KB.
__global__ void wfrag_kernel(const float* __restrict__ W1, unsigned* __restrict__ tab) {
    int t = blockIdx.x * blockDim.x + threadIdx.x;   // 0..1023
    int frag = t >> 6, lane = t & 63;
    int kk = frag >> 2, nn = frag & 3;
    int q = lane >> 4, c = lane & 15;
    int n = nn * 16 + c;
    int k0 = kk * 32 + q * 8;
    unsigned w[4];
#pragma unroll
    for (int p = 0; p < 4; ++p) {
        float lo = W1[(k0 + 2 * p    ) * 64 + n];
        float hi = W1[(k0 + 2 * p + 1) * 64 + n];
        w[p] = pack2(lo, hi);
    }
    unsigned* dst = tab + (frag * 64 + lane) * 4;
    *(uint4*)dst = make_uint4(w[0], w[1], w[2], w[3]);
}

#define ATOMS_PER_BLOCK 4

__global__ __launch_bounds__(256) void force_kernel(
    const float* __restrict__ emb,      // (8192, 64, 128)
    const float* __restrict__ uvec,     // (8192, 64, 3)
    const float* __restrict__ b1,       // (64,)
    const float* __restrict__ W2,       // (64,)
    const float* __restrict__ b2,       // (1,)
    const unsigned short* __restrict__ tab,
    float* __restrict__ out)            // (8192, 3)
{
    const int tid  = threadIdx.x;
    const int wave = tid >> 6;
    const int lane = tid & 63;
    const int q = lane >> 4;
    const int c = lane & 15;

    // B fragments (block-invariant, L1-hot, coalesced: lane i -> 16B at lane*16)
    short8 bfrag[16];
    const short8* tabv = (const short8*)tab;
#pragma unroll
    for (int f = 0; f < 16; ++f) bfrag[f] = tabv[f * 64 + lane];

    float b1v[4], w2v[4];
#pragma unroll
    for (int nn = 0; nn < 4; ++nn) {
        b1v[nn] = b1[nn * 16 + c];
        w2v[nn] = W2[nn * 16 + c];
    }
    const float b2v = b2[0];

    __shared__ float red[ATOMS_PER_BLOCK][4][3];

    const int atom0 = blockIdx.x * ATOMS_PER_BLOCK;

    for (int ai = 0; ai < ATOMS_PER_BLOCK; ++ai) {
        const int atom  = atom0 + ai;
        const int ebase = atom * 64 + wave * 16;          // first edge of this wave's tile
        // A operand: lane supplies row m = c (edge ebase+c), k = kk*32 + q*8 + j
        const float* aptr = emb + (ebase + c) * 128 + q * 8;

        float4 p[8];
#pragma unroll
        for (int kk = 0; kk < 4; ++kk) {
            p[2 * kk]     = *(const float4*)(aptr + kk * 32);
            p[2 * kk + 1] = *(const float4*)(aptr + kk * 32 + 4);
        }
        short8 afrag[4];
#pragma unroll
        for (int kk = 0; kk < 4; ++kk) {
            union { short8 s; unsigned u[4]; } cv;
            cv.u[0] = pack2(p[2 * kk].x,     p[2 * kk].y);
            cv.u[1] = pack2(p[2 * kk].z,     p[2 * kk].w);
            cv.u[2] = pack2(p[2 * kk + 1].x, p[2 * kk + 1].y);
            cv.u[3] = pack2(p[2 * kk + 1].z, p[2 * kk + 1].w);
            afrag[kk] = cv.s;
        }

        f32x4 acc[4] = {{0.f,0.f,0.f,0.f},{0.f,0.f,0.f,0.f},{0.f,0.f,0.f,0.f},{0.f,0.f,0.f,0.f}};
#pragma unroll
        for (int kk = 0; kk < 4; ++kk)
#pragma unroll
            for (int nn = 0; nn < 4; ++nn)
                acc[nn] = __builtin_amdgcn_mfma_f32_16x16x32_bf16(
                    afrag[kk], bfrag[kk * 4 + nn], acc[nn], 0, 0, 0);

        // C/D layout: col (=h within 16-chunk) = c, row (=edge within tile) = q*4 + r
        float fm[4];
#pragma unroll
        for (int r = 0; r < 4; ++r) {
            float s = 0.f;
#pragma unroll
            for (int nn = 0; nn < 4; ++nn) {
                float z  = acc[nn][r] + b1v[nn];
                // shifted softplus: max(z,0) + log1p(exp(-|z|)) - log(2)
                float sp = fmaxf(z, 0.f) + __logf(1.f + __expf(-fabsf(z))) - 0.69314718056f;
                s += sp * w2v[nn];
            }
            fm[r] = s;
        }
        // reduce over the 16 h-columns (lanes sharing quad q, c = 0..15)
#pragma unroll
        for (int m = 1; m < 16; m <<= 1) {
#pragma unroll
            for (int r = 0; r < 4; ++r) fm[r] += __shfl_xor(fm[r], m, 64);
        }
#pragma unroll
        for (int r = 0; r < 4; ++r) fm[r] += b2v;

        // multiply by unit vectors, sum over this wave's 16 edges.
        // lane (q, c<3) handles component x=c for edges q*4+r.
        float s = 0.f;
        if (c < 3) {
            const float* up = uvec + (ebase + q * 4) * 3 + c;
#pragma unroll
            for (int r = 0; r < 4; ++r) s += fm[r] * up[r * 3];
        }
        s += __shfl_xor(s, 16, 64);   // combine quads
        s += __shfl_xor(s, 32, 64);
        if (lane < 3) red[ai][wave][lane] = s;
    }

    __syncthreads();
    if (tid < ATOMS_PER_BLOCK * 3) {
        int ai = tid / 3, x = tid % 3;
        out[(atom0 + ai) * 3 + x] =
            red[ai][0][x] + red[ai][1][x] + red[ai][2][x] + red[ai][3][x];
    }
}

extern "C" void kernel_launch(void* const* d_in, const int* in_sizes, int n_in,
                              void* d_out, int out_size, void* d_ws, size_t ws_size,
                              hipStream_t stream) {
    const float* emb  = (const float*)d_in[0];
    const float* uvec = (const float*)d_in[1];
    const float* W1   = (const float*)d_in[2];
    const float* b1   = (const float*)d_in[3];
    const float* W2   = (const float*)d_in[4];
    const float* b2   = (const float*)d_in[5];
    float* out = (float*)d_out;

    unsigned* tab = (unsigned*)d_ws;   // 16 KB bf16 B-fragment table

    wfrag_kernel<<<4, 256, 0, stream>>>(W1, tab);

    const int atoms = 16 * 512;                       // 8192
    force_kernel<<<atoms / ATOMS_PER_BLOCK, 256, 0, stream>>>(
        emb, uvec, b1, W2, b2, (const unsigned short*)tab, out);
}

// Round 2
// 371.128 us; speedup vs baseline: 1.0051x; 1.0051x over previous
//
#include <hip/hip_runtime.h>

// ForceMapping: out[b,a,x] = sum_n ( ssp(E[b,a,n,:] @ W1 + b1) @ W2 + b2 ) * u[b,a,n,x]
// B=16, At=512, Nbr=64, F=128, H=64. 8192 atoms, 64 edges each.
//
// R2: bfrag moved regs -> LDS (16 KB/block) to cut VGPRs ~160 -> <128 so we get
// 4 waves/SIMD instead of 2 (m69 VGPR quantization). uvec prefetched early.

typedef __attribute__((ext_vector_type(8))) short short8;   // 8 bf16 = 4 VGPRs (MFMA A/B frag)
typedef __attribute__((ext_vector_type(4))) float f32x4;    // MFMA C/D frag

__device__ __forceinline__ unsigned bf16rn(float f) {
    unsigned u = __float_as_uint(f);
    unsigned r = 0x7FFFu + ((u >> 16) & 1u);   // round-to-nearest-even
    return (u + r) >> 16;
}
__device__ __forceinline__ unsigned pack2(float lo, float hi) {
    return bf16rn(lo) | (bf16rn(hi) << 16);
}

// Setup: pre-swizzle W1 (128x64 fp32, row-major [f][h]) into bf16 B-fragments in
// per-lane MFMA order. frag t = kk*4+nn; lane holds B[k=kk*32+q*8+j][n=nn*16+c], j=0..7.
// Table: 16 frags x 64 lanes x 8 bf16 = 16 KB.
__global__ void wfrag_kernel(const float* __restrict__ W1, unsigned* __restrict__ tab) {
    int t = blockIdx.x * blockDim.x + threadIdx.x;   // 0..1023
    int frag = t >> 6, lane = t & 63;
    int kk = frag >> 2, nn = frag & 3;
    int q = lane >> 4, c = lane & 15;
    int n = nn * 16 + c;
    int k0 = kk * 32 + q * 8;
    unsigned w[4];
#pragma unroll
    for (int p = 0; p < 4; ++p) {
        float lo = W1[(k0 + 2 * p    ) * 64 + n];
        float hi = W1[(k0 + 2 * p + 1) * 64 + n];
        w[p] = pack2(lo, hi);
    }
    unsigned* dst = tab + (frag * 64 + lane) * 4;
    *(uint4*)dst = make_uint4(w[0], w[1], w[2], w[3]);
}

#define ATOMS_PER_BLOCK 4

__global__ __launch_bounds__(256, 4) void force_kernel(
    const float* __restrict__ emb,      // (8192, 64, 128)
    const float* __restrict__ uvec,     // (8192, 64, 3)
    const float* __restrict__ b1,       // (64,)
    const float* __restrict__ W2,       // (64,)
    const float* __restrict__ b2,       // (1,)
    const uint4* __restrict__ tab,      // 16 KB bf16 B-fragment table
    float* __restrict__ out)            // (8192, 3)
{
    const int tid  = threadIdx.x;
    const int wave = tid >> 6;
    const int lane = tid & 63;
    const int q = lane >> 4;
    const int c = lane & 15;

    // Stage B-fragment table in LDS (16 KB) — frees 64 VGPRs vs register-resident.
    __shared__ uint4 tab_lds[1024];
    __shared__ float red[ATOMS_PER_BLOCK][4][3];
#pragma unroll
    for (int i = 0; i < 4; ++i) tab_lds[i * 256 + tid] = tab[i * 256 + tid];
    __syncthreads();
    const short8* bfl = (const short8*)tab_lds;   // indexed [frag*64 + lane]

    float b1v[4], w2v[4];
#pragma unroll
    for (int nn = 0; nn < 4; ++nn) {
        b1v[nn] = b1[nn * 16 + c];
        w2v[nn] = W2[nn * 16 + c];
    }
    const float b2v = b2[0];

    const int atom0 = blockIdx.x * ATOMS_PER_BLOCK;

    for (int ai = 0; ai < ATOMS_PER_BLOCK; ++ai) {
        const int ebase = (atom0 + ai) * 64 + wave * 16;  // first edge of this wave's tile

        // Prefetch unit vectors early: lane (q, c<3) -> component c of edges q*4+r.
        float uv[4];
        if (c < 3) {
            const float* up = uvec + (ebase + q * 4) * 3 + c;
#pragma unroll
            for (int r = 0; r < 4; ++r) uv[r] = up[r * 3];
        }

        // A operand: lane supplies row m = c (edge ebase+c), k = kk*32 + q*8 + j
        const float* aptr = emb + (ebase + c) * 128 + q * 8;
        float4 p[8];
#pragma unroll
        for (int kk = 0; kk < 4; ++kk) {
            p[2 * kk]     = *(const float4*)(aptr + kk * 32);
            p[2 * kk + 1] = *(const float4*)(aptr + kk * 32 + 4);
        }
        short8 afrag[4];
#pragma unroll
        for (int kk = 0; kk < 4; ++kk) {
            union { short8 s; unsigned u[4]; } cv;
            cv.u[0] = pack2(p[2 * kk].x,     p[2 * kk].y);
            cv.u[1] = pack2(p[2 * kk].z,     p[2 * kk].w);
            cv.u[2] = pack2(p[2 * kk + 1].x, p[2 * kk + 1].y);
            cv.u[3] = pack2(p[2 * kk + 1].z, p[2 * kk + 1].w);
            afrag[kk] = cv.s;
        }

        f32x4 acc[4] = {{0.f,0.f,0.f,0.f},{0.f,0.f,0.f,0.f},{0.f,0.f,0.f,0.f},{0.f,0.f,0.f,0.f}};
#pragma unroll
        for (int kk = 0; kk < 4; ++kk)
#pragma unroll
            for (int nn = 0; nn < 4; ++nn)
                acc[nn] = __builtin_amdgcn_mfma_f32_16x16x32_bf16(
                    afrag[kk], bfl[(kk * 4 + nn) * 64 + lane], acc[nn], 0, 0, 0);

        // C/D layout: col (=h within 16-chunk) = c, row (=edge within tile) = q*4 + r
        float fm[4];
#pragma unroll
        for (int r = 0; r < 4; ++r) {
            float s = 0.f;
#pragma unroll
            for (int nn = 0; nn < 4; ++nn) {
                float z  = acc[nn][r] + b1v[nn];
                // shifted softplus: max(z,0) + log1p(exp(-|z|)) - log(2)
                float sp = fmaxf(z, 0.f) + __logf(1.f + __expf(-fabsf(z))) - 0.69314718056f;
                s += sp * w2v[nn];
            }
            fm[r] = s;
        }
        // reduce over the 16 h-columns (lanes sharing quad q, c = 0..15)
#pragma unroll
        for (int m = 1; m < 16; m <<= 1) {
#pragma unroll
            for (int r = 0; r < 4; ++r) fm[r] += __shfl_xor(fm[r], m, 64);
        }

        // multiply by unit vectors, sum over this wave's 16 edges.
        float s = 0.f;
        if (c < 3) {
#pragma unroll
            for (int r = 0; r < 4; ++r) s += (fm[r] + b2v) * uv[r];
        }
        s += __shfl_xor(s, 16, 64);   // combine quads
        s += __shfl_xor(s, 32, 64);
        if (lane < 3) red[ai][wave][lane] = s;
    }

    __syncthreads();
    if (tid < ATOMS_PER_BLOCK * 3) {
        int ai = tid / 3, x = tid % 3;
        out[(atom0 + ai) * 3 + x] =
            red[ai][0][x] + red[ai][1][x] + red[ai][2][x] + red[ai][3][x];
    }
}

extern "C" void kernel_launch(void* const* d_in, const int* in_sizes, int n_in,
                              void* d_out, int out_size, void* d_ws, size_t ws_size,
                              hipStream_t stream) {
    const float* emb  = (const float*)d_in[0];
    const float* uvec = (const float*)d_in[1];
    const float* W1   = (const float*)d_in[2];
    const float* b1   = (const float*)d_in[3];
    const float* W2   = (const float*)d_in[4];
    const float* b2   = (const float*)d_in[5];
    float* out = (float*)d_out;

    unsigned* tab = (unsigned*)d_ws;   // 16 KB bf16 B-fragment table

    wfrag_kernel<<<4, 256, 0, stream>>>(W1, tab);

    const int atoms = 16 * 512;                       // 8192
    force_kernel<<<atoms / ATOMS_PER_BLOCK, 256, 0, stream>>>(
        emb, uvec, b1, W2, b2, (const uint4*)tab, out);
}

// Round 3
// 364.643 us; speedup vs baseline: 1.0230x; 1.0178x over previous
//
#include <hip/hip_runtime.h>

// ForceMapping: out[b,a,x] = sum_n ( ssp(E[b,a,n,:] @ W1 + b1) @ W2 + b2 ) * u[b,a,n,x]
// B=16, At=512, Nbr=64, F=128, H=64. 8192 atoms, 64 edges each.
//
// R3: one atom per block (grid 8192) — removes the serial 4-atom loop so memory
// latency is hidden by inter-block overlap (4 blocks/CU resident). W1 fragment
// table built in-kernel from L2-cached W1 (no separate setup launch). emb/uvec
// loads issued first so the tab build overlaps their ~900-cycle latency.

typedef __attribute__((ext_vector_type(8))) short short8;   // 8 bf16 = 4 VGPRs (MFMA A/B frag)
typedef __attribute__((ext_vector_type(4))) float f32x4;    // MFMA C/D frag

__device__ __forceinline__ unsigned bf16rn(float f) {
    unsigned u = __float_as_uint(f);
    unsigned r = 0x7FFFu + ((u >> 16) & 1u);   // round-to-nearest-even
    return (u + r) >> 16;
}
__device__ __forceinline__ unsigned pack2(float lo, float hi) {
    return bf16rn(lo) | (bf16rn(hi) << 16);
}

__global__ __launch_bounds__(256, 4) void force_kernel(
    const float* __restrict__ emb,      // (8192, 64, 128)
    const float* __restrict__ uvec,     // (8192, 64, 3)
    const float* __restrict__ W1,       // (128, 64) row-major [f][h]
    const float* __restrict__ b1,       // (64,)
    const float* __restrict__ W2,       // (64,)
    const float* __restrict__ b2,       // (1,)
    float* __restrict__ out)            // (8192, 3)
{
    const int tid  = threadIdx.x;
    const int wave = tid >> 6;
    const int lane = tid & 63;
    const int q = lane >> 4;
    const int c = lane & 15;
    const int atom  = blockIdx.x;
    const int ebase = atom * 64 + wave * 16;   // this wave's 16 edges

    __shared__ uint4 tab[1024];   // 16 KB: bf16 B-fragments, [frag][lane]
    __shared__ float red[4][3];

    // ---- 1) issue the latency-critical global loads FIRST ----
    // A operand: lane supplies row m = c (edge ebase+c), k = kk*32 + q*8 + j
    const float* aptr = emb + (ebase + c) * 128 + q * 8;
    float4 p[8];
#pragma unroll
    for (int kk = 0; kk < 4; ++kk) {
        p[2 * kk]     = *(const float4*)(aptr + kk * 32);
        p[2 * kk + 1] = *(const float4*)(aptr + kk * 32 + 4);
    }
    float uv[4];
    if (c < 3) {
        const float* up = uvec + (ebase + q * 4) * 3 + c;
#pragma unroll
        for (int r = 0; r < 4; ++r) uv[r] = up[r * 3];
    }

    // ---- 2) build W1 fragment table (overlaps emb load latency) ----
    // frag f = kk*4+nn; lane holds B[k=kk*32+q*8+j][n=nn*16+c], j=0..7 packed pairs.
#pragma unroll
    for (int t = 0; t < 4; ++t) {
        const int frag = wave * 4 + t;         // 256 threads cover 16 frags x 64 lanes
        const int kk = frag >> 2, nn = frag & 3;
        const int k0 = kk * 32 + q * 8;
        const int n  = nn * 16 + c;
        uint4 w;
        w.x = pack2(W1[(k0 + 0) * 64 + n], W1[(k0 + 1) * 64 + n]);
        w.y = pack2(W1[(k0 + 2) * 64 + n], W1[(k0 + 3) * 64 + n]);
        w.z = pack2(W1[(k0 + 4) * 64 + n], W1[(k0 + 5) * 64 + n]);
        w.w = pack2(W1[(k0 + 6) * 64 + n], W1[(k0 + 7) * 64 + n]);
        tab[frag * 64 + lane] = w;
    }
    float b1v[4], w2v[4];
#pragma unroll
    for (int nn = 0; nn < 4; ++nn) {
        b1v[nn] = b1[nn * 16 + c];
        w2v[nn] = W2[nn * 16 + c];
    }
    const float b2v = b2[0];
    __syncthreads();
    const short8* bfl = (const short8*)tab;

    // ---- 3) convert A to bf16 fragments, run MFMAs ----
    short8 afrag[4];
#pragma unroll
    for (int kk = 0; kk < 4; ++kk) {
        union { short8 s; unsigned u[4]; } cv;
        cv.u[0] = pack2(p[2 * kk].x,     p[2 * kk].y);
        cv.u[1] = pack2(p[2 * kk].z,     p[2 * kk].w);
        cv.u[2] = pack2(p[2 * kk + 1].x, p[2 * kk + 1].y);
        cv.u[3] = pack2(p[2 * kk + 1].z, p[2 * kk + 1].w);
        afrag[kk] = cv.s;
    }

    f32x4 acc[4] = {{0.f,0.f,0.f,0.f},{0.f,0.f,0.f,0.f},{0.f,0.f,0.f,0.f},{0.f,0.f,0.f,0.f}};
#pragma unroll
    for (int kk = 0; kk < 4; ++kk)
#pragma unroll
        for (int nn = 0; nn < 4; ++nn)
            acc[nn] = __builtin_amdgcn_mfma_f32_16x16x32_bf16(
                afrag[kk], bfl[(kk * 4 + nn) * 64 + lane], acc[nn], 0, 0, 0);

    // ---- 4) epilogue: bias + ssp + W2 dot, reduce over H, apply unit vectors ----
    // C/D layout: col (=h within 16-chunk) = c, row (=edge within tile) = q*4 + r
    float fm[4];
#pragma unroll
    for (int r = 0; r < 4; ++r) {
        float s = 0.f;
#pragma unroll
        for (int nn = 0; nn < 4; ++nn) {
            float z  = acc[nn][r] + b1v[nn];
            // shifted softplus: max(z,0) + log1p(exp(-|z|)) - log(2)
            float sp = fmaxf(z, 0.f) + __logf(1.f + __expf(-fabsf(z))) - 0.69314718056f;
            s += sp * w2v[nn];
        }
        fm[r] = s;
    }
#pragma unroll
    for (int m = 1; m < 16; m <<= 1) {        // reduce over the 16 h-columns
#pragma unroll
        for (int r = 0; r < 4; ++r) fm[r] += __shfl_xor(fm[r], m, 64);
    }

    float s = 0.f;
    if (c < 3) {                              // lane (q, c<3): component c, edges q*4+r
#pragma unroll
        for (int r = 0; r < 4; ++r) s += (fm[r] + b2v) * uv[r];
    }
    s += __shfl_xor(s, 16, 64);               // combine quads
    s += __shfl_xor(s, 32, 64);
    if (lane < 3) red[wave][lane] = s;

    __syncthreads();
    if (tid < 3)
        out[atom * 3 + tid] = red[0][tid] + red[1][tid] + red[2][tid] + red[3][tid];
}

extern "C" void kernel_launch(void* const* d_in, const int* in_sizes, int n_in,
                              void* d_out, int out_size, void* d_ws, size_t ws_size,
                              hipStream_t stream) {
    const float* emb  = (const float*)d_in[0];
    const float* uvec = (const float*)d_in[1];
    const float* W1   = (const float*)d_in[2];
    const float* b1   = (const float*)d_in[3];
    const float* W2   = (const float*)d_in[4];
    const float* b2   = (const float*)d_in[5];
    float* out = (float*)d_out;

    const int atoms = 16 * 512;   // 8192
    force_kernel<<<atoms, 256, 0, stream>>>(emb, uvec, W1, b1, W2, b2, out);
}